// Round 1
// baseline (348.153 us; speedup 1.0000x reference)
//
#include <hip/hip_runtime.h>
#include <math.h>

// Problem constants (from setup_inputs): B=16, S=8192, Q=1024, K=256, fp32.
#define BB 16
#define SS 8192
#define KK 256
#define QQ 1024

static constexpr float C2L2E = 2.88539008177792681f;  // 2*log2(e)
static constexpr float FLOAT_MIN_V = -100000.0f;

__device__ __forceinline__ float wave_sum(float v) {
#pragma unroll
  for (int off = 32; off >= 1; off >>= 1) v += __shfl_xor(v, off, 64);
  return v;
}

// ---------------------------------------------------------------------------
// Kernel A: qb2[b][k] = 2log2e * (query[b,:] . W[k,:] + b_attr[k])
// 16 blocks x 256 threads; each wave handles k = w, w+4, ... with the full
// query row preloaded into 4 float4 regs per lane (1024 floats / 64 lanes).
// ---------------------------------------------------------------------------
__global__ __launch_bounds__(256) void qproj_kernel(
    const float* __restrict__ query, const float* __restrict__ W,
    const float* __restrict__ b_attr, float* __restrict__ qb2) {
  const int b = blockIdx.x;
  const int lane = threadIdx.x & 63;
  const int w = threadIdx.x >> 6;
  const float4* q4 = (const float4*)(query + (size_t)b * QQ);
  float4 qr[4];
#pragma unroll
  for (int i = 0; i < 4; ++i) qr[i] = q4[i * 64 + lane];
  for (int k = w; k < KK; k += 4) {
    const float4* w4 = (const float4*)(W + (size_t)k * QQ);
    float acc = 0.f;
#pragma unroll
    for (int i = 0; i < 4; ++i) {
      float4 wv = w4[i * 64 + lane];
      acc = fmaf(wv.x, qr[i].x, acc);
      acc = fmaf(wv.y, qr[i].y, acc);
      acc = fmaf(wv.z, qr[i].z, acc);
      acc = fmaf(wv.w, qr[i].w, acc);
    }
    acc = wave_sum(acc);
    if (lane == 0) qb2[b * KK + k] = C2L2E * (acc + b_attr[k]);
  }
}

// ---------------------------------------------------------------------------
// Kernel B: e[b,s] = sum_k tanh(keys[b,s,k] + q[b,k] + b_attr[k]) * V[k]
// tanh(x) = 1 - 2*rcp(1 + exp2(2log2e*x)); arg = fma(key, 2log2e, qb2).
// contribution = V - 2*V*r  =>  e = sumV + sum(nv2 * r).
// One wave per row: 64 lanes x float4 = the whole 256-elem row.
// ---------------------------------------------------------------------------
#define EROWS 128  // rows per block -> 1024 blocks
__global__ __launch_bounds__(256) void energy_kernel(
    const float* __restrict__ keys, const float* __restrict__ V_attr,
    const float* __restrict__ qb2, float* __restrict__ e) {
  const int blk = blockIdx.x;
  const int b = blk / (SS / EROWS);
  const int s0 = (blk % (SS / EROWS)) * EROWS;
  const int lane = threadIdx.x & 63;
  const int w = threadIdx.x >> 6;

  const float4 v4 = ((const float4*)V_attr)[lane];
  const float sv = wave_sum(v4.x + v4.y + v4.z + v4.w);  // sum over all V
  const float4 nv2 =
      make_float4(-2.f * v4.x, -2.f * v4.y, -2.f * v4.z, -2.f * v4.w);
  const float4 qb = ((const float4*)qb2)[b * (KK / 4) + lane];

  for (int s = s0 + w; s < s0 + EROWS; s += 4) {
    const float4 kv = ((const float4*)(keys + (size_t)(b * SS + s) * KK))[lane];
    float r0 = __builtin_amdgcn_rcpf(
        1.f + __builtin_amdgcn_exp2f(fmaf(kv.x, C2L2E, qb.x)));
    float r1 = __builtin_amdgcn_rcpf(
        1.f + __builtin_amdgcn_exp2f(fmaf(kv.y, C2L2E, qb.y)));
    float r2 = __builtin_amdgcn_rcpf(
        1.f + __builtin_amdgcn_exp2f(fmaf(kv.z, C2L2E, qb.z)));
    float r3 = __builtin_amdgcn_rcpf(
        1.f + __builtin_amdgcn_exp2f(fmaf(kv.w, C2L2E, qb.w)));
    float p = fmaf(nv2.x, r0,
                   fmaf(nv2.y, r1, fmaf(nv2.z, r2, nv2.w * r3)));
    p = wave_sum(p);
    if (lane == 0) e[b * SS + s] = p + sv;
  }
}

// ---------------------------------------------------------------------------
// Kernel C: per-batch softmax over S. Applies kv_mask, writes scores to
// d_out, and zeroes the ctx region (d_out is poisoned 0xAA) before kernel D.
// 16 blocks x 1024 threads, 8 elements/thread.
// ---------------------------------------------------------------------------
__global__ __launch_bounds__(1024) void softmax_kernel(
    const float* __restrict__ e, const float* __restrict__ mask,
    float* __restrict__ scores, float* __restrict__ ctx) {
  const int b = blockIdx.x;
  const int tid = threadIdx.x;
  const int lane = tid & 63;
  const int wid = tid >> 6;
  __shared__ float red[16];

  float ev[8];
  float m = -3.4e38f;
#pragma unroll
  for (int i = 0; i < 8; ++i) {
    const int s = tid + i * 1024;
    const float mk = mask[b * SS + s];
    float x = e[b * SS + s];
    x = mk * x + (1.f - mk) * FLOAT_MIN_V;
    ev[i] = x;
    m = fmaxf(m, x);
  }
#pragma unroll
  for (int off = 32; off >= 1; off >>= 1) m = fmaxf(m, __shfl_xor(m, off, 64));
  if (lane == 0) red[wid] = m;
  __syncthreads();
  if (wid == 0) {
    float t = red[lane & 15];
#pragma unroll
    for (int off = 8; off >= 1; off >>= 1) t = fmaxf(t, __shfl_xor(t, off, 64));
    if (lane == 0) red[0] = t;
  }
  __syncthreads();
  m = red[0];
  __syncthreads();  // red is reused below

  float pv[8];
  float l = 0.f;
#pragma unroll
  for (int i = 0; i < 8; ++i) {
    pv[i] = __expf(ev[i] - m);
    l += pv[i];
  }
  l = wave_sum(l);
  if (lane == 0) red[wid] = l;
  __syncthreads();
  if (wid == 0) {
    float t = red[lane & 15];
#pragma unroll
    for (int off = 8; off >= 1; off >>= 1) t += __shfl_xor(t, off, 64);
    if (lane == 0) red[0] = t;
  }
  __syncthreads();
  const float inv = 1.f / red[0];
#pragma unroll
  for (int i = 0; i < 8; ++i) scores[b * SS + tid + i * 1024] = pv[i] * inv;

  if (tid < KK) ctx[b * KK + tid] = 0.f;
}

// ---------------------------------------------------------------------------
// Kernel D: ctx[b,k] = sum_s scores[b,s] * values[b,s,k]
// One wave per row (float4/lane); 4-wave LDS combine, then one atomicAdd per
// (block, k): 1024 blocks * 256 = 262144 atomics over 4096 addresses.
// ---------------------------------------------------------------------------
#define CROWS 128  // rows per block -> 1024 blocks
__global__ __launch_bounds__(256) void ctx_kernel(
    const float* __restrict__ values, const float* __restrict__ scores,
    float* __restrict__ ctx) {
  const int blk = blockIdx.x;
  const int b = blk / (SS / CROWS);
  const int s0 = (blk % (SS / CROWS)) * CROWS;
  const int lane = threadIdx.x & 63;
  const int w = threadIdx.x >> 6;

  float4 acc = make_float4(0.f, 0.f, 0.f, 0.f);
  for (int s = s0 + w; s < s0 + CROWS; s += 4) {
    const float p = scores[b * SS + s];
    const float4 v =
        ((const float4*)(values + (size_t)(b * SS + s) * KK))[lane];
    acc.x = fmaf(p, v.x, acc.x);
    acc.y = fmaf(p, v.y, acc.y);
    acc.z = fmaf(p, v.z, acc.z);
    acc.w = fmaf(p, v.w, acc.w);
  }

  __shared__ float cacc[4][KK];
  ((float4*)&cacc[w][0])[lane] = acc;
  __syncthreads();
  const int t = threadIdx.x;
  const float sum = cacc[0][t] + cacc[1][t] + cacc[2][t] + cacc[3][t];
  atomicAdd(&ctx[b * KK + t], sum);
}

extern "C" void kernel_launch(void* const* d_in, const int* in_sizes, int n_in,
                              void* d_out, int out_size, void* d_ws,
                              size_t ws_size, hipStream_t stream) {
  const float* query = (const float*)d_in[0];   // [B,Q]
  const float* keys = (const float*)d_in[1];    // [B,S,K]
  const float* values = (const float*)d_in[2];  // [B,S,K]
  const float* mask = (const float*)d_in[3];    // [B,S,1]
  const float* W = (const float*)d_in[4];       // [K,Q]
  const float* b_attr = (const float*)d_in[5];  // [K]
  const float* V_attr = (const float*)d_in[6];  // [K]

  float* scores = (float*)d_out;        // [B,S,1] flat first
  float* ctx = scores + BB * SS;        // [B,K] after

  float* qb2 = (float*)d_ws;            // [B,K]   16 KiB
  float* e = qb2 + BB * KK;             // [B,S]  512 KiB

  qproj_kernel<<<BB, 256, 0, stream>>>(query, W, b_attr, qb2);
  energy_kernel<<<BB * (SS / EROWS), 256, 0, stream>>>(keys, V_attr, qb2, e);
  softmax_kernel<<<BB, 1024, 0, stream>>>(e, mask, scores, ctx);
  ctx_kernel<<<BB * (SS / CROWS), 256, 0, stream>>>(values, scores, ctx);
}

// Round 2
// 299.664 us; speedup vs baseline: 1.1618x; 1.1618x over previous
//
#include <hip/hip_runtime.h>
#include <math.h>

// Problem constants (from setup_inputs): B=16, S=8192, Q=1024, K=256, fp32.
#define BB 16
#define SS 8192
#define KK 256
#define QQ 1024

static constexpr float C2L2E = 2.88539008177792681f;  // 2*log2(e)
static constexpr float FLOAT_MIN_V = -100000.0f;

__device__ __forceinline__ float wave_sum(float v) {
#pragma unroll
  for (int off = 32; off >= 1; off >>= 1) v += __shfl_xor(v, off, 64);
  return v;
}

// ---------------------------------------------------------------------------
// Kernel A: qb2[b][k] = 2log2e * (query[b,:] . W[k,:] + b_attr[k])
// Grid: BB*64 blocks x 256 threads. Block handles (b, 4 consecutive k), one
// wave per k. Lane layout: lane reads float4 j*64+lane of both W-row and
// query-row (dot product is order-invariant). W re-read per b hits L2/L3.
// ---------------------------------------------------------------------------
__global__ __launch_bounds__(256) void qproj_kernel(
    const float* __restrict__ query, const float* __restrict__ W,
    const float* __restrict__ b_attr, float* __restrict__ qb2) {
  const int blk = blockIdx.x;
  const int b = blk >> 6;            // 64 blocks per batch
  const int kg = blk & 63;           // k-group of 4
  const int lane = threadIdx.x & 63;
  const int w = threadIdx.x >> 6;
  const int k = kg * 4 + w;

  const float4* q4 = (const float4*)(query + (size_t)b * QQ);
  const float4* w4 = (const float4*)(W + (size_t)k * QQ);
  float acc = 0.f;
#pragma unroll
  for (int j = 0; j < 4; ++j) {
    const float4 qv = q4[j * 64 + lane];
    const float4 wv = w4[j * 64 + lane];
    acc = fmaf(wv.x, qv.x, acc);
    acc = fmaf(wv.y, qv.y, acc);
    acc = fmaf(wv.z, qv.z, acc);
    acc = fmaf(wv.w, qv.w, acc);
  }
  acc = wave_sum(acc);
  if (lane == 0) qb2[b * KK + k] = C2L2E * (acc + b_attr[k]);
}

// ---------------------------------------------------------------------------
// Kernel B: e[b,s] = sum_k tanh(keys[b,s,k] + q[b,k] + b_attr[k]) * V[k]
// tanh(x) = 1 - 2*rcp(1 + exp2(2log2e*x)); arg = fma(key, 2log2e, qb2).
// contribution = V - 2Vr  =>  e = sumV + sum(-2V * r).
// One wave per row (64 lanes x float4 = 256 floats); 16 contiguous rows per
// wave with 1-deep prefetch; EROWS=64 -> 2048 blocks -> 32 waves/CU.
// ---------------------------------------------------------------------------
#define EROWS 64
__global__ __launch_bounds__(256) void energy_kernel(
    const float* __restrict__ keys, const float* __restrict__ V_attr,
    const float* __restrict__ qb2, float* __restrict__ e) {
  const int blk = blockIdx.x;
  const int b = blk / (SS / EROWS);
  const int lane = threadIdx.x & 63;
  const int w = threadIdx.x >> 6;
  const int s0 = (blk % (SS / EROWS)) * EROWS + w * (EROWS / 4);

  const float4 v4 = ((const float4*)V_attr)[lane];
  const float sv = wave_sum(v4.x + v4.y + v4.z + v4.w);  // sum over all V
  const float4 nv2 =
      make_float4(-2.f * v4.x, -2.f * v4.y, -2.f * v4.z, -2.f * v4.w);
  const float4 qb = ((const float4*)qb2)[b * (KK / 4) + lane];

  const float* rowbase = keys + (size_t)(b * SS + s0) * KK;
  float4 kv = ((const float4*)rowbase)[lane];
  for (int i = 0; i < EROWS / 4; ++i) {
    const float4 cur = kv;
    if (i < EROWS / 4 - 1)
      kv = ((const float4*)(rowbase + (size_t)(i + 1) * KK))[lane];
    float r0 = __builtin_amdgcn_rcpf(
        1.f + __builtin_amdgcn_exp2f(fmaf(cur.x, C2L2E, qb.x)));
    float r1 = __builtin_amdgcn_rcpf(
        1.f + __builtin_amdgcn_exp2f(fmaf(cur.y, C2L2E, qb.y)));
    float r2 = __builtin_amdgcn_rcpf(
        1.f + __builtin_amdgcn_exp2f(fmaf(cur.z, C2L2E, qb.z)));
    float r3 = __builtin_amdgcn_rcpf(
        1.f + __builtin_amdgcn_exp2f(fmaf(cur.w, C2L2E, qb.w)));
    float p = fmaf(nv2.x, r0,
                   fmaf(nv2.y, r1, fmaf(nv2.z, r2, nv2.w * r3)));
    p = wave_sum(p);
    if (lane == 0) e[b * SS + s0 + i] = p + sv;
  }
}

// ---------------------------------------------------------------------------
// Kernel C: per-batch masked softmax over S; writes scores to d_out.
// 16 blocks x 1024 threads, 8 elements/thread.
// ---------------------------------------------------------------------------
__global__ __launch_bounds__(1024) void softmax_kernel(
    const float* __restrict__ e, const float* __restrict__ mask,
    float* __restrict__ scores) {
  const int b = blockIdx.x;
  const int tid = threadIdx.x;
  const int lane = tid & 63;
  const int wid = tid >> 6;
  __shared__ float red[16];

  float ev[8];
  float m = -3.4e38f;
#pragma unroll
  for (int i = 0; i < 8; ++i) {
    const int s = tid + i * 1024;
    const float mk = mask[b * SS + s];
    float x = e[b * SS + s];
    x = mk * x + (1.f - mk) * FLOAT_MIN_V;
    ev[i] = x;
    m = fmaxf(m, x);
  }
#pragma unroll
  for (int off = 32; off >= 1; off >>= 1) m = fmaxf(m, __shfl_xor(m, off, 64));
  if (lane == 0) red[wid] = m;
  __syncthreads();
  if (wid == 0) {
    float t = red[lane & 15];
#pragma unroll
    for (int off = 8; off >= 1; off >>= 1) t = fmaxf(t, __shfl_xor(t, off, 64));
    if (lane == 0) red[0] = t;
  }
  __syncthreads();
  m = red[0];
  __syncthreads();  // red reused below

  float pv[8];
  float l = 0.f;
#pragma unroll
  for (int i = 0; i < 8; ++i) {
    pv[i] = __expf(ev[i] - m);
    l += pv[i];
  }
  l = wave_sum(l);
  if (lane == 0) red[wid] = l;
  __syncthreads();
  if (wid == 0) {
    float t = red[lane & 15];
#pragma unroll
    for (int off = 8; off >= 1; off >>= 1) t += __shfl_xor(t, off, 64);
    if (lane == 0) red[0] = t;
  }
  __syncthreads();
  const float inv = 1.f / red[0];
#pragma unroll
  for (int i = 0; i < 8; ++i) scores[b * SS + tid + i * 1024] = pv[i] * inv;
}

// ---------------------------------------------------------------------------
// Kernel D1: per-block partial ctx sums -> ws (deterministic, no atomics).
// One wave per row, 16 contiguous rows/wave w/ prefetch; CROWS=64 -> 2048
// blocks -> 32 waves/CU. Block-combined through LDS, partial per block.
// ---------------------------------------------------------------------------
#define CROWS 64
__global__ __launch_bounds__(256) void ctx_partial_kernel(
    const float* __restrict__ values, const float* __restrict__ scores,
    float* __restrict__ part) {
  const int blk = blockIdx.x;
  const int b = blk / (SS / CROWS);
  const int lane = threadIdx.x & 63;
  const int w = threadIdx.x >> 6;
  const int s0 = (blk % (SS / CROWS)) * CROWS + w * (CROWS / 4);

  const float* rowbase = values + (size_t)(b * SS + s0) * KK;
  float4 kv = ((const float4*)rowbase)[lane];
  float4 acc = make_float4(0.f, 0.f, 0.f, 0.f);
  for (int i = 0; i < CROWS / 4; ++i) {
    const float4 cur = kv;
    if (i < CROWS / 4 - 1)
      kv = ((const float4*)(rowbase + (size_t)(i + 1) * KK))[lane];
    const float p = scores[b * SS + s0 + i];
    acc.x = fmaf(p, cur.x, acc.x);
    acc.y = fmaf(p, cur.y, acc.y);
    acc.z = fmaf(p, cur.z, acc.z);
    acc.w = fmaf(p, cur.w, acc.w);
  }

  __shared__ float cacc[4][KK];
  ((float4*)&cacc[w][0])[lane] = acc;
  __syncthreads();
  const int t = threadIdx.x;
  part[(size_t)blk * KK + t] =
      cacc[0][t] + cacc[1][t] + cacc[2][t] + cacc[3][t];
}

// ---------------------------------------------------------------------------
// Kernel D2: ctx[b][k] = sum over the batch's 128 block-partials.
// ---------------------------------------------------------------------------
__global__ __launch_bounds__(256) void ctx_reduce_kernel(
    const float* __restrict__ part, float* __restrict__ ctx) {
  const int b = blockIdx.x;
  const int t = threadIdx.x;
  const float* p = part + (size_t)b * (SS / CROWS) * KK + t;
  float s = 0.f;
#pragma unroll 8
  for (int j = 0; j < SS / CROWS; ++j) s += p[(size_t)j * KK];
  ctx[b * KK + t] = s;
}

extern "C" void kernel_launch(void* const* d_in, const int* in_sizes, int n_in,
                              void* d_out, int out_size, void* d_ws,
                              size_t ws_size, hipStream_t stream) {
  const float* query = (const float*)d_in[0];   // [B,Q]
  const float* keys = (const float*)d_in[1];    // [B,S,K]
  const float* values = (const float*)d_in[2];  // [B,S,K]
  const float* mask = (const float*)d_in[3];    // [B,S,1]
  const float* W = (const float*)d_in[4];       // [K,Q]
  const float* b_attr = (const float*)d_in[5];  // [K]
  const float* V_attr = (const float*)d_in[6];  // [K]

  float* scores = (float*)d_out;  // [B,S,1] flat first
  float* ctx = scores + BB * SS;  // [B,K] after

  float* qb2 = (float*)d_ws;        // [B,K]            16 KiB
  float* e = qb2 + BB * KK;         // [B,S]           512 KiB
  float* part = e + BB * SS;        // [2048][K]         2 MiB

  qproj_kernel<<<BB * (KK / 4), 256, 0, stream>>>(query, W, b_attr, qb2);
  energy_kernel<<<BB * (SS / EROWS), 256, 0, stream>>>(keys, V_attr, qb2, e);
  softmax_kernel<<<BB, 1024, 0, stream>>>(e, mask, scores);
  ctx_partial_kernel<<<BB * (SS / CROWS), 256, 0, stream>>>(values, scores,
                                                            part);
  ctx_reduce_kernel<<<BB, 256, 0, stream>>>(part, ctx);
}

// Round 4
// 276.133 us; speedup vs baseline: 1.2608x; 1.0852x over previous
//
#include <hip/hip_runtime.h>
#include <math.h>

// Problem constants (from setup_inputs): B=16, S=8192, Q=1024, K=256, fp32.
#define BB 16
#define SS 8192
#define KK 256
#define QQ 1024

static constexpr float C2L2E = 2.88539008177792681f;  // 2*log2(e)
static constexpr float L2E = 1.44269504088896341f;    // log2(e)
static constexpr float FLOAT_MIN_V = -100000.0f;

// Native vector type: __builtin_nontemporal_load rejects HIP_vector_type.
typedef float floatx4 __attribute__((ext_vector_type(4)));

__device__ __forceinline__ float wave_sum(float v) {
#pragma unroll
  for (int off = 32; off >= 1; off >>= 1) v += __shfl_xor(v, off, 64);
  return v;
}

__device__ __forceinline__ float wave_max(float v) {
#pragma unroll
  for (int off = 32; off >= 1; off >>= 1) v = fmaxf(v, __shfl_xor(v, off, 64));
  return v;
}

__device__ __forceinline__ floatx4 ldnt(const float* p) {
  return __builtin_nontemporal_load((const floatx4*)p);
}

// ---------------------------------------------------------------------------
// Kernel A: qb2[b][k] = 2log2e * (query[b,:] . W[k,:] + b_attr[k])
// 1024 blocks x 256 threads; block = (b, 4 consecutive k), one wave per k.
// ---------------------------------------------------------------------------
__global__ __launch_bounds__(256) void qproj_kernel(
    const float* __restrict__ query, const float* __restrict__ W,
    const float* __restrict__ b_attr, float* __restrict__ qb2) {
  const int blk = blockIdx.x;
  const int b = blk >> 6;   // 64 blocks per batch
  const int kg = blk & 63;  // k-group of 4
  const int lane = threadIdx.x & 63;
  const int w = threadIdx.x >> 6;
  const int k = kg * 4 + w;

  const float4* q4 = (const float4*)(query + (size_t)b * QQ);
  const float4* w4 = (const float4*)(W + (size_t)k * QQ);
  float acc = 0.f;
#pragma unroll
  for (int j = 0; j < 4; ++j) {
    const float4 qv = q4[j * 64 + lane];
    const float4 wv = w4[j * 64 + lane];
    acc = fmaf(wv.x, qv.x, acc);
    acc = fmaf(wv.y, qv.y, acc);
    acc = fmaf(wv.z, qv.z, acc);
    acc = fmaf(wv.w, qv.w, acc);
  }
  acc = wave_sum(acc);
  if (lane == 0) qb2[b * KK + k] = C2L2E * (acc + b_attr[k]);
}

// ---------------------------------------------------------------------------
// Kernel B (fused): single pass over keys AND values with online softmax.
// Per row s: e_s = sumV + sum_k(-2*V_k * rcp(1+exp2(fma(key,2log2e,qb2)))),
// x_s = mask*e_s + (1-mask)*FLOAT_MIN (stored to e for the scores pass),
// then online update of (m, l, acc[k] = sum exp(x-m)*v). 4 waves combined
// through LDS into one block partial (m, l, acc[256]).
// FROWS=64 -> 2048 blocks (8 blocks/CU, 32 waves/CU), 16 rows/wave.
// ---------------------------------------------------------------------------
#define FROWS 64
__global__ __launch_bounds__(256) void fused_kernel(
    const float* __restrict__ keys, const float* __restrict__ values,
    const float* __restrict__ mask, const float* __restrict__ V_attr,
    const float* __restrict__ qb2, float* __restrict__ e,
    float* __restrict__ part_m, float* __restrict__ part_l,
    float* __restrict__ part_acc) {
  const int blk = blockIdx.x;
  const int b = blk / (SS / FROWS);
  const int lane = threadIdx.x & 63;
  const int w = threadIdx.x >> 6;
  const int s0 = (blk % (SS / FROWS)) * FROWS + w * (FROWS / 4);

  const float4 v4 = ((const float4*)V_attr)[lane];
  const float sv = wave_sum(v4.x + v4.y + v4.z + v4.w);  // sum of all V
  const float4 nv2 =
      make_float4(-2.f * v4.x, -2.f * v4.y, -2.f * v4.z, -2.f * v4.w);
  const float4 qb = ((const float4*)qb2)[b * (KK / 4) + lane];

  const float* krow = keys + (size_t)(b * SS + s0) * KK;
  const float* vrow = values + (size_t)(b * SS + s0) * KK;
  floatx4 kf = ldnt(krow + 4 * lane);
  floatx4 vf = ldnt(vrow + 4 * lane);

  float m = -3.4e38f, l = 0.f;
  float4 acc = make_float4(0.f, 0.f, 0.f, 0.f);
  for (int i = 0; i < FROWS / 4; ++i) {
    const floatx4 ck = kf;
    const floatx4 cv = vf;
    if (i < FROWS / 4 - 1) {
      kf = ldnt(krow + (size_t)(i + 1) * KK + 4 * lane);
      vf = ldnt(vrow + (size_t)(i + 1) * KK + 4 * lane);
    }
    const float mk = mask[b * SS + s0 + i];
    float r0 = __builtin_amdgcn_rcpf(
        1.f + __builtin_amdgcn_exp2f(fmaf(ck.x, C2L2E, qb.x)));
    float r1 = __builtin_amdgcn_rcpf(
        1.f + __builtin_amdgcn_exp2f(fmaf(ck.y, C2L2E, qb.y)));
    float r2 = __builtin_amdgcn_rcpf(
        1.f + __builtin_amdgcn_exp2f(fmaf(ck.z, C2L2E, qb.z)));
    float r3 = __builtin_amdgcn_rcpf(
        1.f + __builtin_amdgcn_exp2f(fmaf(ck.w, C2L2E, qb.w)));
    float p = fmaf(nv2.x, r0, fmaf(nv2.y, r1, fmaf(nv2.z, r2, nv2.w * r3)));
    p = wave_sum(p);  // butterfly: all lanes hold the row sum
    const float es = p + sv;
    const float x = mk * es + (1.f - mk) * FLOAT_MIN_V;
    if (lane == 0) e[b * SS + s0 + i] = x;  // masked energy for scores pass
    const float newm = fmaxf(m, x);
    const float sc = __builtin_amdgcn_exp2f((m - newm) * L2E);
    const float pe = __builtin_amdgcn_exp2f((x - newm) * L2E);
    l = fmaf(l, sc, pe);
    acc.x = fmaf(acc.x, sc, pe * cv.x);
    acc.y = fmaf(acc.y, sc, pe * cv.y);
    acc.z = fmaf(acc.z, sc, pe * cv.z);
    acc.w = fmaf(acc.w, sc, pe * cv.w);
    m = newm;
  }

  // Combine the 4 waves' online states into one block partial.
  __shared__ float lacc[4][KK];
  __shared__ float lm[4], ll[4];
  ((float4*)&lacc[w][0])[lane] = acc;
  if (lane == 0) {
    lm[w] = m;
    ll[w] = l;
  }
  __syncthreads();
  const float M = fmaxf(fmaxf(lm[0], lm[1]), fmaxf(lm[2], lm[3]));
  const float w0 = __builtin_amdgcn_exp2f((lm[0] - M) * L2E);
  const float w1 = __builtin_amdgcn_exp2f((lm[1] - M) * L2E);
  const float w2 = __builtin_amdgcn_exp2f((lm[2] - M) * L2E);
  const float w3 = __builtin_amdgcn_exp2f((lm[3] - M) * L2E);
  const int t = threadIdx.x;
  const float ca =
      fmaf(w0, lacc[0][t], fmaf(w1, lacc[1][t], fmaf(w2, lacc[2][t], w3 * lacc[3][t])));
  part_acc[(size_t)blk * KK + t] = ca;
  if (t == 0) {
    part_m[blk] = M;
    part_l[blk] = fmaf(w0, ll[0], fmaf(w1, ll[1], fmaf(w2, ll[2], w3 * ll[3])));
  }
}

// ---------------------------------------------------------------------------
// Kernel C (finalize): per batch, merge 128 block partials -> (M, L),
// ctx[b][k] = sum_j scale_j*acc_j[k] / L, scores[b][s] = exp(x_s - M)/L.
// 16 blocks x 1024 threads.
// ---------------------------------------------------------------------------
__global__ __launch_bounds__(1024) void finalize_kernel(
    const float* __restrict__ part_m, const float* __restrict__ part_l,
    const float* __restrict__ part_acc, const float* __restrict__ e,
    float* __restrict__ scores, float* __restrict__ ctx) {
  const int b = blockIdx.x;
  const int tid = threadIdx.x;
  const int lane = tid & 63;
  constexpr int NP = SS / FROWS;  // 128 partials per batch
  __shared__ float sm[NP], sl[NP], sscale[NP];
  __shared__ float cred[4][KK];

  if (tid < NP) {
    sm[tid] = part_m[b * NP + tid];
    sl[tid] = part_l[b * NP + tid];
  }
  __syncthreads();

  // Every wave independently computes M and L (uniform result).
  const float M = wave_max(fmaxf(sm[lane], sm[lane + 64]));
  const float L = wave_sum(
      fmaf(__builtin_amdgcn_exp2f((sm[lane] - M) * L2E), sl[lane],
           __builtin_amdgcn_exp2f((sm[lane + 64] - M) * L2E) * sl[lane + 64]));
  if (tid < NP) sscale[tid] = __builtin_amdgcn_exp2f((sm[tid] - M) * L2E);
  __syncthreads();

  // ctx: 4 groups of 256 threads each cover 32 partials, LDS-combined.
  const int g = tid >> 8;  // 0..3
  const int k = tid & 255;
  float s = 0.f;
#pragma unroll 8
  for (int j = g * 32; j < g * 32 + 32; ++j)
    s = fmaf(sscale[j], part_acc[(size_t)(b * NP + j) * KK + k], s);
  cred[g][k] = s;
  __syncthreads();
  const float invL = 1.f / L;
  if (tid < KK)
    ctx[b * KK + tid] =
        (cred[0][tid] + cred[1][tid] + cred[2][tid] + cred[3][tid]) * invL;

  // scores from stored masked energies.
#pragma unroll
  for (int i = 0; i < 8; ++i) {
    const int s_idx = tid + i * 1024;
    const float x = e[b * SS + s_idx];
    scores[b * SS + s_idx] = __builtin_amdgcn_exp2f((x - M) * L2E) * invL;
  }
}

extern "C" void kernel_launch(void* const* d_in, const int* in_sizes, int n_in,
                              void* d_out, int out_size, void* d_ws,
                              size_t ws_size, hipStream_t stream) {
  const float* query = (const float*)d_in[0];   // [B,Q]
  const float* keys = (const float*)d_in[1];    // [B,S,K]
  const float* values = (const float*)d_in[2];  // [B,S,K]
  const float* mask = (const float*)d_in[3];    // [B,S,1]
  const float* W = (const float*)d_in[4];       // [K,Q]
  const float* b_attr = (const float*)d_in[5];  // [K]
  const float* V_attr = (const float*)d_in[6];  // [K]

  float* scores = (float*)d_out;  // [B,S,1] flat first
  float* ctx = scores + BB * SS;  // [B,K] after

  float* qb2 = (float*)d_ws;                     // [B,K]        16 KiB
  float* e = qb2 + BB * KK;                      // [B,S]       512 KiB
  float* part_m = e + BB * SS;                   // [2048]        8 KiB
  float* part_l = part_m + BB * (SS / FROWS);    // [2048]        8 KiB
  float* part_acc = part_l + BB * (SS / FROWS);  // [2048][K]     2 MiB

  qproj_kernel<<<BB * (KK / 4), 256, 0, stream>>>(query, W, b_attr, qb2);
  fused_kernel<<<BB * (SS / FROWS), 256, 0, stream>>>(
      keys, values, mask, V_attr, qb2, e, part_m, part_l, part_acc);
  finalize_kernel<<<BB, 1024, 0, stream>>>(part_m, part_l, part_acc, e,
                                           scores, ctx);
}

// Round 5
// 273.067 us; speedup vs baseline: 1.2750x; 1.0112x over previous
//
#include <hip/hip_runtime.h>
#include <math.h>

// Problem constants (from setup_inputs): B=16, S=8192, Q=1024, K=256, fp32.
#define BB 16
#define SS 8192
#define KK 256
#define QQ 1024

static constexpr float C2L2E = 2.88539008177792681f;  // 2*log2(e)
static constexpr float L2E = 1.44269504088896341f;    // log2(e)
static constexpr float FLOAT_MIN_V = -100000.0f;

// Native vector type: __builtin_nontemporal_load rejects HIP_vector_type.
typedef float floatx4 __attribute__((ext_vector_type(4)));

__device__ __forceinline__ float wave_sum(float v) {
#pragma unroll
  for (int off = 32; off >= 1; off >>= 1) v += __shfl_xor(v, off, 64);
  return v;
}

__device__ __forceinline__ floatx4 ldnt(const float* p) {
  return __builtin_nontemporal_load((const floatx4*)p);
}

// ---------------------------------------------------------------------------
// Kernel A: qb2[b][k] = 2log2e * (query[b,:] . W[k,:] + b_attr[k])
// 1024 blocks x 256 threads; block = (b, 4 consecutive k), one wave per k.
// ---------------------------------------------------------------------------
__global__ __launch_bounds__(256) void qproj_kernel(
    const float* __restrict__ query, const float* __restrict__ W,
    const float* __restrict__ b_attr, float* __restrict__ qb2) {
  const int blk = blockIdx.x;
  const int b = blk >> 6;   // 64 blocks per batch
  const int kg = blk & 63;  // k-group of 4
  const int lane = threadIdx.x & 63;
  const int w = threadIdx.x >> 6;
  const int k = kg * 4 + w;

  const float4* q4 = (const float4*)(query + (size_t)b * QQ);
  const float4* w4 = (const float4*)(W + (size_t)k * QQ);
  float acc = 0.f;
#pragma unroll
  for (int j = 0; j < 4; ++j) {
    const float4 qv = q4[j * 64 + lane];
    const float4 wv = w4[j * 64 + lane];
    acc = fmaf(wv.x, qv.x, acc);
    acc = fmaf(wv.y, qv.y, acc);
    acc = fmaf(wv.z, qv.z, acc);
    acc = fmaf(wv.w, qv.w, acc);
  }
  acc = wave_sum(acc);
  if (lane == 0) qb2[b * KK + k] = C2L2E * (acc + b_attr[k]);
}

// ---------------------------------------------------------------------------
// Kernel B (fused, no online max): single pass over keys+values.
// e_s = sumV + sum_k(-2*V_k*rcp(1+exp2(fma(key,2log2e,qb2)))); energies are
// bounded by sum|V| <= 16, so exp(e_s) cannot overflow fp32 -> fixed M=0.
// pe_s = exp(mask*e + (1-mask)*FLOAT_MIN) stored to pbuf; partials are plain
// sums (l, acc[k]). 2 rows/iter (interleaved butterflies), 2-row prefetch.
// FROWS=64 -> 2048 blocks (8 blocks/CU, 32 waves/CU), 16 rows/wave.
// ---------------------------------------------------------------------------
#define FROWS 64
__global__ __launch_bounds__(256) void fused_kernel(
    const float* __restrict__ keys, const float* __restrict__ values,
    const float* __restrict__ mask, const float* __restrict__ V_attr,
    const float* __restrict__ qb2, float* __restrict__ pbuf,
    float* __restrict__ part_l, float* __restrict__ part_acc) {
  const int blk = blockIdx.x;
  const int b = blk / (SS / FROWS);
  const int lane = threadIdx.x & 63;
  const int w = threadIdx.x >> 6;
  const int s0 = (blk % (SS / FROWS)) * FROWS + w * (FROWS / 4);

  const float4 v4 = ((const float4*)V_attr)[lane];
  const float sv = wave_sum(v4.x + v4.y + v4.z + v4.w);  // sum of all V
  const float4 nv2 =
      make_float4(-2.f * v4.x, -2.f * v4.y, -2.f * v4.z, -2.f * v4.w);
  const float4 qb = ((const float4*)qb2)[b * (KK / 4) + lane];

  const float* krow = keys + (size_t)(b * SS + s0) * KK;
  const float* vrow = values + (size_t)(b * SS + s0) * KK;
  floatx4 kf0 = ldnt(krow + 4 * lane);
  floatx4 vf0 = ldnt(vrow + 4 * lane);
  floatx4 kf1 = ldnt(krow + KK + 4 * lane);
  floatx4 vf1 = ldnt(vrow + KK + 4 * lane);

  float l0 = 0.f, l1 = 0.f;
  float4 acc0 = make_float4(0.f, 0.f, 0.f, 0.f);
  float4 acc1 = make_float4(0.f, 0.f, 0.f, 0.f);
  for (int i = 0; i < FROWS / 4; i += 2) {
    const floatx4 ck0 = kf0, cv0 = vf0, ck1 = kf1, cv1 = vf1;
    if (i + 2 < FROWS / 4) {
      kf0 = ldnt(krow + (size_t)(i + 2) * KK + 4 * lane);
      vf0 = ldnt(vrow + (size_t)(i + 2) * KK + 4 * lane);
      kf1 = ldnt(krow + (size_t)(i + 3) * KK + 4 * lane);
      vf1 = ldnt(vrow + (size_t)(i + 3) * KK + 4 * lane);
    }
    const float mk0 = mask[b * SS + s0 + i];
    const float mk1 = mask[b * SS + s0 + i + 1];

    float p0, p1;
    {
      float a0 = __builtin_amdgcn_rcpf(
          1.f + __builtin_amdgcn_exp2f(fmaf(ck0.x, C2L2E, qb.x)));
      float a1 = __builtin_amdgcn_rcpf(
          1.f + __builtin_amdgcn_exp2f(fmaf(ck0.y, C2L2E, qb.y)));
      float a2 = __builtin_amdgcn_rcpf(
          1.f + __builtin_amdgcn_exp2f(fmaf(ck0.z, C2L2E, qb.z)));
      float a3 = __builtin_amdgcn_rcpf(
          1.f + __builtin_amdgcn_exp2f(fmaf(ck0.w, C2L2E, qb.w)));
      p0 = fmaf(nv2.x, a0, fmaf(nv2.y, a1, fmaf(nv2.z, a2, nv2.w * a3)));
    }
    {
      float a0 = __builtin_amdgcn_rcpf(
          1.f + __builtin_amdgcn_exp2f(fmaf(ck1.x, C2L2E, qb.x)));
      float a1 = __builtin_amdgcn_rcpf(
          1.f + __builtin_amdgcn_exp2f(fmaf(ck1.y, C2L2E, qb.y)));
      float a2 = __builtin_amdgcn_rcpf(
          1.f + __builtin_amdgcn_exp2f(fmaf(ck1.z, C2L2E, qb.z)));
      float a3 = __builtin_amdgcn_rcpf(
          1.f + __builtin_amdgcn_exp2f(fmaf(ck1.w, C2L2E, qb.w)));
      p1 = fmaf(nv2.x, a0, fmaf(nv2.y, a1, fmaf(nv2.z, a2, nv2.w * a3)));
    }
    // Two interleaved butterflies (independent DS chains).
#pragma unroll
    for (int off = 32; off >= 1; off >>= 1) {
      p0 += __shfl_xor(p0, off, 64);
      p1 += __shfl_xor(p1, off, 64);
    }
    const float x0 = mk0 * (p0 + sv) + (1.f - mk0) * FLOAT_MIN_V;
    const float x1 = mk1 * (p1 + sv) + (1.f - mk1) * FLOAT_MIN_V;
    const float pe0 = __builtin_amdgcn_exp2f(x0 * L2E);
    const float pe1 = __builtin_amdgcn_exp2f(x1 * L2E);
    if (lane == 0) {
      pbuf[b * SS + s0 + i] = pe0;
      pbuf[b * SS + s0 + i + 1] = pe1;
    }
    l0 += pe0;
    l1 += pe1;
    acc0.x = fmaf(pe0, cv0.x, acc0.x);
    acc0.y = fmaf(pe0, cv0.y, acc0.y);
    acc0.z = fmaf(pe0, cv0.z, acc0.z);
    acc0.w = fmaf(pe0, cv0.w, acc0.w);
    acc1.x = fmaf(pe1, cv1.x, acc1.x);
    acc1.y = fmaf(pe1, cv1.y, acc1.y);
    acc1.z = fmaf(pe1, cv1.z, acc1.z);
    acc1.w = fmaf(pe1, cv1.w, acc1.w);
  }
  const float l = l0 + l1;
  const float4 acc = make_float4(acc0.x + acc1.x, acc0.y + acc1.y,
                                 acc0.z + acc1.z, acc0.w + acc1.w);

  // Plain-sum combine of the 4 waves into one block partial.
  __shared__ float lacc[4][KK];
  __shared__ float ll[4];
  ((float4*)&lacc[w][0])[lane] = acc;
  if (lane == 0) ll[w] = l;
  __syncthreads();
  const int t = threadIdx.x;
  part_acc[(size_t)blk * KK + t] =
      lacc[0][t] + lacc[1][t] + lacc[2][t] + lacc[3][t];
  if (t == 0) part_l[blk] = ll[0] + ll[1] + ll[2] + ll[3];
}

// ---------------------------------------------------------------------------
// Kernel C (finalize): per batch, L = sum of 128 partial l's;
// ctx[b][k] = sum_j acc_j[k] / L; scores[b][s] = pbuf[s] / L.
// 16 blocks x 1024 threads.
// ---------------------------------------------------------------------------
__global__ __launch_bounds__(1024) void finalize_kernel(
    const float* __restrict__ part_l, const float* __restrict__ part_acc,
    const float* __restrict__ pbuf, float* __restrict__ scores,
    float* __restrict__ ctx) {
  const int b = blockIdx.x;
  const int tid = threadIdx.x;
  const int lane = tid & 63;
  constexpr int NP = SS / FROWS;  // 128 partials per batch
  __shared__ float sl[NP];
  __shared__ float cred[4][KK];

  if (tid < NP) sl[tid] = part_l[b * NP + tid];
  __syncthreads();

  const float L = wave_sum(sl[lane] + sl[lane + 64]);  // uniform per wave
  const float invL = 1.f / L;

  // ctx: 4 groups of 256 threads each cover 32 partials, LDS-combined.
  const int g = tid >> 8;  // 0..3
  const int k = tid & 255;
  float s = 0.f;
#pragma unroll 8
  for (int j = g * 32; j < g * 32 + 32; ++j)
    s += part_acc[(size_t)(b * NP + j) * KK + k];
  cred[g][k] = s;
  __syncthreads();
  if (tid < KK)
    ctx[b * KK + tid] =
        (cred[0][tid] + cred[1][tid] + cred[2][tid] + cred[3][tid]) * invL;

  // scores = unnormalized probs * invL.
#pragma unroll
  for (int i = 0; i < 8; ++i) {
    const int s_idx = tid + i * 1024;
    scores[b * SS + s_idx] = pbuf[b * SS + s_idx] * invL;
  }
}

extern "C" void kernel_launch(void* const* d_in, const int* in_sizes, int n_in,
                              void* d_out, int out_size, void* d_ws,
                              size_t ws_size, hipStream_t stream) {
  const float* query = (const float*)d_in[0];   // [B,Q]
  const float* keys = (const float*)d_in[1];    // [B,S,K]
  const float* values = (const float*)d_in[2];  // [B,S,K]
  const float* mask = (const float*)d_in[3];    // [B,S,1]
  const float* W = (const float*)d_in[4];       // [K,Q]
  const float* b_attr = (const float*)d_in[5];  // [K]
  const float* V_attr = (const float*)d_in[6];  // [K]

  float* scores = (float*)d_out;  // [B,S,1] flat first
  float* ctx = scores + BB * SS;  // [B,K] after

  float* qb2 = (float*)d_ws;                   // [B,K]        16 KiB
  float* pbuf = qb2 + BB * KK;                 // [B,S]       512 KiB
  float* part_l = pbuf + BB * SS;              // [2048]        8 KiB
  float* part_acc = part_l + BB * (SS / FROWS);  // [2048][K]   2 MiB

  qproj_kernel<<<BB * (KK / 4), 256, 0, stream>>>(query, W, b_attr, qb2);
  fused_kernel<<<BB * (SS / FROWS), 256, 0, stream>>>(
      keys, values, mask, V_attr, qb2, pbuf, part_l, part_acc);
  finalize_kernel<<<BB, 1024, 0, stream>>>(part_l, part_acc, pbuf, scores,
                                           ctx);
}